// Round 1
// baseline (388.399 us; speedup 1.0000x reference)
//
#include <hip/hip_runtime.h>

// Problem constants (fixed by setup_inputs): x_t = a_t * x_{t-1} + u_t
#define BB 8
#define TT 4096
#define DD 1024
#define SS 128            // segments along T
#define TSEG (TT / SS)    // 32 timesteps per segment

// ---------------------------------------------------------------------------
// Kernel 1: per-segment affine reduction.
// Each block handles one (b, s); thread i handles channels [4i, 4i+3] (float4).
// Computes A = prod(a_t), U = scan-with-zero-init over the segment.
// ---------------------------------------------------------------------------
__global__ __launch_bounds__(256) void seg_reduce(
    const float* __restrict__ a, const float* __restrict__ u,
    float* __restrict__ wsA, float* __restrict__ wsU) {
  const int blk = blockIdx.x;           // b*SS + s
  const int b = blk / SS;
  const int s = blk % SS;
  const int d4 = threadIdx.x * 4;

  const size_t base = ((size_t)b * TT + (size_t)s * TSEG) * DD + d4;
  const float4* __restrict__ ap = (const float4*)(a + base);
  const float4* __restrict__ up = (const float4*)(u + base);

  float4 A = make_float4(1.f, 1.f, 1.f, 1.f);
  float4 U = make_float4(0.f, 0.f, 0.f, 0.f);

#pragma unroll 8
  for (int t = 0; t < TSEG; ++t) {
    const float4 av = ap[(size_t)t * (DD / 4)];
    const float4 uv = up[(size_t)t * (DD / 4)];
    U.x = fmaf(av.x, U.x, uv.x);
    U.y = fmaf(av.y, U.y, uv.y);
    U.z = fmaf(av.z, U.z, uv.z);
    U.w = fmaf(av.w, U.w, uv.w);
    A.x *= av.x;
    A.y *= av.y;
    A.z *= av.z;
    A.w *= av.w;
  }

  const size_t w = ((size_t)b * SS + s) * DD + d4;
  *(float4*)(wsA + w) = A;
  *(float4*)(wsU + w) = U;
}

// ---------------------------------------------------------------------------
// Kernel 2: sequential scan across segment summaries (tiny: 12 MiB traffic).
// One thread per (b, d) channel; emits state entering each segment.
// ---------------------------------------------------------------------------
__global__ __launch_bounds__(256) void seg_scan(
    const float* __restrict__ x0, const float* __restrict__ wsA,
    const float* __restrict__ wsU, float* __restrict__ xstart) {
  const int tid = blockIdx.x * 256 + threadIdx.x;  // 0 .. BB*DD-1
  const int b = tid / DD;
  const int d = tid % DD;

  float x = x0[(size_t)b * DD + d];
  size_t idx = ((size_t)b * SS) * DD + d;
#pragma unroll 4
  for (int s = 0; s < SS; ++s) {
    xstart[idx] = x;
    x = fmaf(wsA[idx], x, wsU[idx]);
    idx += DD;
  }
}

// ---------------------------------------------------------------------------
// Kernel 3: replay each segment from its known entry state, write output.
// ---------------------------------------------------------------------------
__global__ __launch_bounds__(256) void seg_apply(
    const float* __restrict__ a, const float* __restrict__ u,
    const float* __restrict__ xstart, float* __restrict__ out) {
  const int blk = blockIdx.x;
  const int b = blk / SS;
  const int s = blk % SS;
  const int d4 = threadIdx.x * 4;

  const size_t base = ((size_t)b * TT + (size_t)s * TSEG) * DD + d4;
  const float4* __restrict__ ap = (const float4*)(a + base);
  const float4* __restrict__ up = (const float4*)(u + base);
  float4* __restrict__ op = (float4*)(out + base);

  const size_t w = ((size_t)b * SS + s) * DD + d4;
  float4 x = *(const float4*)(xstart + w);

#pragma unroll 8
  for (int t = 0; t < TSEG; ++t) {
    const float4 av = ap[(size_t)t * (DD / 4)];
    const float4 uv = up[(size_t)t * (DD / 4)];
    x.x = fmaf(av.x, x.x, uv.x);
    x.y = fmaf(av.y, x.y, uv.y);
    x.z = fmaf(av.z, x.z, uv.z);
    x.w = fmaf(av.w, x.w, uv.w);
    op[(size_t)t * (DD / 4)] = x;
  }
}

extern "C" void kernel_launch(void* const* d_in, const int* in_sizes, int n_in,
                              void* d_out, int out_size, void* d_ws, size_t ws_size,
                              hipStream_t stream) {
  const float* x0 = (const float*)d_in[0];  // [B, D]
  const float* a  = (const float*)d_in[1];  // [B, T, D]
  const float* u  = (const float*)d_in[2];  // [B, T, D]
  float* out = (float*)d_out;               // [B, T, D]

  const size_t seg_elems = (size_t)BB * SS * DD;  // 1M floats = 4 MiB
  float* wsA    = (float*)d_ws;
  float* wsU    = wsA + seg_elems;
  float* xstart = wsU + seg_elems;

  // Pass 1: per-segment (A, U) summaries. 1024 blocks x 256 threads.
  seg_reduce<<<BB * SS, 256, 0, stream>>>(a, u, wsA, wsU);
  // Pass 2: scan across segments per channel. 32 blocks x 256 threads.
  seg_scan<<<(BB * DD) / 256, 256, 0, stream>>>(x0, wsA, wsU, xstart);
  // Pass 3: replay with correct entry states, write output.
  seg_apply<<<BB * SS, 256, 0, stream>>>(a, u, xstart, out);
}

// Round 2
// 378.227 us; speedup vs baseline: 1.0269x; 1.0269x over previous
//
#include <hip/hip_runtime.h>

// x_t = a_t * x_{t-1} + u_t ; B=8, T=4096, D=1024, fp32.
// 3-pass chunked scan. R2: register-prefetch pipelines in pass 1/3 (R1 showed
// VGPR=36 => compiler issued loads serially, 2.65 TB/s effective), LDS-parallel
// pass 2 (R1's 32-block serial-chain kernel was latency-bound).
#define BB 8
#define TT 4096
#define DD 1024
#define SS 128            // segments along T
#define TSEG (TT / SS)    // 32 timesteps per segment
#define STR (DD / 4)      // float4 row stride

static __device__ __forceinline__ float4 ffma4(const float4 a, const float4 x,
                                               const float4 u) {
  return make_float4(fmaf(a.x, x.x, u.x), fmaf(a.y, x.y, u.y),
                     fmaf(a.z, x.z, u.z), fmaf(a.w, x.w, u.w));
}
static __device__ __forceinline__ float4 fmul4(const float4 a, const float4 b) {
  return make_float4(a.x * b.x, a.y * b.y, a.z * b.z, a.w * b.w);
}

// ---------------------------------------------------------------------------
// Pass 1: per-segment affine summary (A = prod a, U = zero-init scan).
// Block = one (b, s); thread = 4 channels. Explicit 2-deep load pipeline:
// keeps >=2 float4-pair loads in flight per wave so the serial FMA chain
// doesn't serialize the memory stream.
// ---------------------------------------------------------------------------
__global__ __launch_bounds__(256) void seg_reduce(
    const float* __restrict__ a, const float* __restrict__ u,
    float* __restrict__ wsA, float* __restrict__ wsU) {
  const int b = blockIdx.x >> 7;        // / SS
  const int s = blockIdx.x & (SS - 1);
  const int d4 = threadIdx.x << 2;

  const size_t base = ((size_t)b * TT + (size_t)s * TSEG) * DD + d4;
  const float4* __restrict__ ap = (const float4*)(a + base);
  const float4* __restrict__ up = (const float4*)(u + base);

  float4 A = make_float4(1.f, 1.f, 1.f, 1.f);
  float4 U = make_float4(0.f, 0.f, 0.f, 0.f);

  // pipeline: regs hold iterations t (cur) and t+1 (next)
  float4 ac = ap[0], uc = up[0];
  float4 an = ap[STR], un = up[STR];

#pragma unroll 4
  for (int t = 0; t < TSEG; ++t) {
    const float4 av = ac, uv = uc;
    ac = an; uc = un;
    const int tn = (t + 2 < TSEG) ? (t + 2) : (TSEG - 1);  // tail: cheap re-load
    an = ap[(size_t)tn * STR];
    un = up[(size_t)tn * STR];
    U = ffma4(av, U, uv);
    A = fmul4(A, av);
  }

  const size_t w = ((size_t)b * SS + s) * DD + d4;
  *(float4*)(wsA + w) = A;
  *(float4*)(wsU + w) = U;
}

// ---------------------------------------------------------------------------
// Pass 2: scan across segment summaries. Block = 64 channels x all SS segments
// staged in LDS (coalesced 256B global loads). Wave w composes segment chunk
// [32w, 32w+32) per channel, cross-wave prefix via LDS, then replays to emit
// xstart[b][s][d] (state entering each segment). Serial depth ~70 FMA.
// ---------------------------------------------------------------------------
__global__ __launch_bounds__(256) void seg_scan(
    const float* __restrict__ x0, const float* __restrict__ wsA,
    const float* __restrict__ wsU, float* __restrict__ xstart) {
  __shared__ float ldsA[SS * 64];       // [s][ch] : 32 KiB
  __shared__ float ldsU[SS * 64];       // 32 KiB
  __shared__ float wsumA[4][64];        // per-wave chunk transform
  __shared__ float wsumU[4][64];

  const int b  = blockIdx.x >> 4;       // 16 channel-groups per b
  const int d0 = (blockIdx.x & 15) << 6;
  const int ch = threadIdx.x & 63;
  const int wv = threadIdx.x >> 6;      // 0..3

  // stage summaries: wave-coalesced (fixed s, 64 consecutive d per instr)
#pragma unroll 8
  for (int it = 0; it < SS / 4; ++it) {
    const int s = (it << 2) + wv;
    const size_t g = ((size_t)b * SS + s) * DD + d0 + ch;
    ldsA[s * 64 + ch] = wsA[g];
    ldsU[s * 64 + ch] = wsU[g];
  }
  __syncthreads();

  // wave-chunk compose: segments [32w, 32w+32)
  float Ac = 1.f, Uc = 0.f;
  const int s0 = wv * (SS / 4);
#pragma unroll 8
  for (int k = 0; k < SS / 4; ++k) {
    const float As = ldsA[(s0 + k) * 64 + ch];
    const float Us = ldsU[(s0 + k) * 64 + ch];
    Uc = fmaf(As, Uc, Us);
    Ac *= As;
  }
  wsumA[wv][ch] = Ac;
  wsumU[wv][ch] = Uc;
  __syncthreads();

  // entry state for this wave's chunk: apply earlier chunks to x0 in order
  float x = x0[(size_t)b * DD + d0 + ch];
  for (int w2 = 0; w2 < wv; ++w2)
    x = fmaf(wsumA[w2][ch], x, wsumU[w2][ch]);

  // replay: emit state entering each segment (coalesced 256B stores)
#pragma unroll 8
  for (int k = 0; k < SS / 4; ++k) {
    const int s = s0 + k;
    xstart[((size_t)b * SS + s) * DD + d0 + ch] = x;
    x = fmaf(ldsA[s * 64 + ch], x, ldsU[s * 64 + ch]);
  }
}

// ---------------------------------------------------------------------------
// Pass 3: replay each segment from its entry state; same load pipeline as
// pass 1, plus streaming float4 output stores.
// ---------------------------------------------------------------------------
__global__ __launch_bounds__(256) void seg_apply(
    const float* __restrict__ a, const float* __restrict__ u,
    const float* __restrict__ xstart, float* __restrict__ out) {
  const int b = blockIdx.x >> 7;
  const int s = blockIdx.x & (SS - 1);
  const int d4 = threadIdx.x << 2;

  const size_t base = ((size_t)b * TT + (size_t)s * TSEG) * DD + d4;
  const float4* __restrict__ ap = (const float4*)(a + base);
  const float4* __restrict__ up = (const float4*)(u + base);
  float4* __restrict__ op = (float4*)(out + base);

  const size_t w = ((size_t)b * SS + s) * DD + d4;
  float4 x = *(const float4*)(xstart + w);

  float4 ac = ap[0], uc = up[0];
  float4 an = ap[STR], un = up[STR];

#pragma unroll 4
  for (int t = 0; t < TSEG; ++t) {
    const float4 av = ac, uv = uc;
    ac = an; uc = un;
    const int tn = (t + 2 < TSEG) ? (t + 2) : (TSEG - 1);
    an = ap[(size_t)tn * STR];
    un = up[(size_t)tn * STR];
    x = ffma4(av, x, uv);
    op[(size_t)t * STR] = x;
  }
}

extern "C" void kernel_launch(void* const* d_in, const int* in_sizes, int n_in,
                              void* d_out, int out_size, void* d_ws, size_t ws_size,
                              hipStream_t stream) {
  const float* x0 = (const float*)d_in[0];  // [B, D]
  const float* a  = (const float*)d_in[1];  // [B, T, D]
  const float* u  = (const float*)d_in[2];  // [B, T, D]
  float* out = (float*)d_out;               // [B, T, D]

  const size_t seg_elems = (size_t)BB * SS * DD;  // 1M floats = 4 MiB
  float* wsA    = (float*)d_ws;
  float* wsU    = wsA + seg_elems;
  float* xstart = wsU + seg_elems;

  seg_reduce<<<BB * SS, 256, 0, stream>>>(a, u, wsA, wsU);
  seg_scan<<<BB * (DD / 64), 256, 0, stream>>>(x0, wsA, wsU, xstart);
  seg_apply<<<BB * SS, 256, 0, stream>>>(a, u, xstart, out);
}